// Round 1
// 248.976 us; speedup vs baseline: 1.1055x; 1.1055x over previous
//
#include <hip/hip_runtime.h>
#include <math.h>

constexpr int Bn = 64, Lc = 1024, Lq = 128, Dd = 128;

typedef __attribute__((ext_vector_type(8))) short short8_t;  // 8 bf16
typedef __attribute__((ext_vector_type(4))) short short4_t;  // 4 bf16
typedef __attribute__((ext_vector_type(4))) float f32x4;

__device__ __forceinline__ short f2bf(float x) {
    unsigned u = __float_as_uint(x);
    u += 0x7FFFu + ((u >> 16) & 1u);   // round-to-nearest-even
    return (short)(u >> 16);
}

constexpr int AS = 132;   // [row][d] LDS stride (shorts)
constexpr int TS = 70;    // k1 transpose buf stride
constexpr int CTS = 68;   // k2 CT staging stride (shorts)
constexpr int PS = 68;    // k2 P^T tile stride (shorts)
constexpr int TBS = 36;   // k2 out-transpose stride (shorts)

// XCD swizzle: same-b blocks share n%8 -> same XCD under round-robin dispatch.
__device__ __forceinline__ void decode_bid(int n, int& b, int& blk) {
    b = (n & 7) * 8 + ((n >> 3) & 7);
    blk = n >> 6;
}

// ================== k1: prep tiles + S + sums (NO E16/ET16 stores, no atomics) ==================
__global__ __launch_bounds__(256) void k1_fused(
    const float* __restrict__ C, const float* __restrict__ Q,
    const int* __restrict__ Cmask, const int* __restrict__ Qmask,
    const float* __restrict__ w_c, const float* __restrict__ w_q,
    const float* __restrict__ w_mul, const float* __restrict__ bias,
    short* __restrict__ CW16, short* __restrict__ CT16,
    short* __restrict__ Q16, short* __restrict__ QT16,
    float* __restrict__ s0f, float* __restrict__ s1f,
    float* __restrict__ colpart, float* __restrict__ rowsumInv)
{
    __shared__ short Abuf[64 * AS];    // C*w_mul bf16, [i][d]
    __shared__ short Bbuf[128 * AS];   // Q bf16, [j][d]; first 128*TS doubles as Tbuf
    __shared__ float s0L[64], cmL[64], s1L[128], qmL[128];
    __shared__ float colL[4 * 128];
    short* Tbuf = Bbuf;

    int b, blk; decode_bid(blockIdx.x, b, blk);
    int i0 = blk * 64, tid = threadIdx.x;

    // ---- phase 1: C tile -> Abuf (cw), Tbuf (cm*C, [d][i]), s0, cm ----
    const float4* C4 = (const float4*)(C + ((size_t)(b * Lc + i0)) * Dd);
    #pragma unroll
    for (int k = 0; k < 8; ++k) {
        int idx = tid + k * 256;
        int i = idx >> 5, d4 = idx & 31;
        float4 v = C4[idx];
        float4 wm = ((const float4*)w_mul)[d4];
        short4_t cw; cw[0]=f2bf(v.x*wm.x); cw[1]=f2bf(v.y*wm.y); cw[2]=f2bf(v.z*wm.z); cw[3]=f2bf(v.w*wm.w);
        *(short4_t*)&Abuf[i * AS + d4 * 4] = cw;
        float cm = (Cmask[b * Lc + i0 + i] != 0) ? 1.0f : 0.0f;
        Tbuf[(d4*4+0)*TS + i] = f2bf(cm * v.x);
        Tbuf[(d4*4+1)*TS + i] = f2bf(cm * v.y);
        Tbuf[(d4*4+2)*TS + i] = f2bf(cm * v.z);
        Tbuf[(d4*4+3)*TS + i] = f2bf(cm * v.w);
        float4 wc = ((const float4*)w_c)[d4];
        float dot = v.x*wc.x + v.y*wc.y + v.z*wc.z + v.w*wc.w;
        #pragma unroll
        for (int off = 1; off < 32; off <<= 1) dot += __shfl_xor(dot, off, 64);
        if ((tid & 31) == 0) { s0L[i] = dot; cmL[i] = cm; s0f[b * Lc + i0 + i] = dot; }
    }
    __syncthreads();

    // ---- phase 2: CT16 + CW16 out ----
    #pragma unroll
    for (int k = 0; k < 8; ++k) {
        int idx = tid + k * 256;
        int d = idx >> 4, i4 = idx & 15;
        *(short4_t*)&CT16[((size_t)(b * Dd + d)) * Lc + i0 + i4 * 4] =
            *(short4_t*)&Tbuf[d * TS + i4 * 4];
    }
    #pragma unroll
    for (int k = 0; k < 4; ++k) {
        int idx = tid + k * 256;
        int i = idx >> 4, h = idx & 15;
        *(short8_t*)&CW16[((size_t)(b * Lc + i0 + i)) * Dd + h * 8] =
            *(short8_t*)&Abuf[i * AS + h * 8];
    }
    __syncthreads();

    // ---- phase 3: Q -> Bbuf, s1, qm ----
    const float4* Q4 = (const float4*)(Q + (size_t)b * Lq * Dd);
    #pragma unroll
    for (int k = 0; k < 16; ++k) {
        int idx = tid + k * 256;
        int j = idx >> 5, d4 = idx & 31;
        float4 v = Q4[idx];
        short4_t qv; qv[0]=f2bf(v.x); qv[1]=f2bf(v.y); qv[2]=f2bf(v.z); qv[3]=f2bf(v.w);
        *(short4_t*)&Bbuf[j * AS + d4 * 4] = qv;
        float4 wq = ((const float4*)w_q)[d4];
        float dot = v.x*wq.x + v.y*wq.y + v.z*wq.z + v.w*wq.w;
        #pragma unroll
        for (int off = 1; off < 32; off <<= 1) dot += __shfl_xor(dot, off, 64);
        if ((tid & 31) == 0) {
            s1L[j] = dot;
            qmL[j] = (Qmask[b * Lq + j] != 0) ? 1.0f : 0.0f;
            if (blk == 0) s1f[b * Lq + j] = dot;
        }
    }
    __syncthreads();

    // ---- phase 4: MFMA S = Cw @ Q^T ----
    int w = tid >> 6, lane = tid & 63, lm = lane & 15, quad = lane >> 4;
    int iw = i0 + w * 16;
    f32x4 acc[8];
    #pragma unroll
    for (int t = 0; t < 8; ++t) acc[t] = (f32x4){0.f,0.f,0.f,0.f};
    #pragma unroll
    for (int ks = 0; ks < 4; ++ks) {
        short8_t a = *(short8_t*)&Abuf[(w * 16 + lm) * AS + ks * 32 + quad * 8];
        #pragma unroll
        for (int jt = 0; jt < 8; ++jt) {
            short8_t bf = *(short8_t*)&Bbuf[(jt * 16 + lm) * AS + ks * 32 + quad * 8];
            acc[jt] = __builtin_amdgcn_mfma_f32_16x16x32_bf16(a, bf, acc[jt], 0, 0, 0);
        }
    }

    // ---- phase 5: exp + rowsumInv + col partials (no global E stores) ----
    float s0v[4], cmv[4];
    #pragma unroll
    for (int r = 0; r < 4; ++r) {
        s0v[r] = s0L[w * 16 + quad * 4 + r];
        cmv[r] = cmL[w * 16 + quad * 4 + r];
    }
    float bb = bias[0];
    float rowpart[4] = {0.f, 0.f, 0.f, 0.f};
    #pragma unroll
    for (int jt = 0; jt < 8; ++jt) {
        int j = jt * 16 + lm;
        float s1 = s1L[j] + bb;
        float qm = qmL[j];
        float cs = 0.f;
        #pragma unroll
        for (int r = 0; r < 4; ++r) {
            float e = __expf(acc[jt][r] + s0v[r] + s1);
            rowpart[r] += qm * e;
            cs += cmv[r] * e;
        }
        cs += __shfl_xor(cs, 16, 64);
        cs += __shfl_xor(cs, 32, 64);
        if (lane < 16) colL[w * 128 + j] = cs;
    }
    #pragma unroll
    for (int r = 0; r < 4; ++r) {
        float v = rowpart[r];
        v += __shfl_xor(v, 1, 64); v += __shfl_xor(v, 2, 64);
        v += __shfl_xor(v, 4, 64); v += __shfl_xor(v, 8, 64);
        if (lm == 0) rowsumInv[b * Lc + iw + quad * 4 + r] = 1.0f / v;
    }
    __syncthreads();
    if (tid < 128)
        colpart[((size_t)b * 16 + blk) * Lq + tid] =
            colL[tid] + colL[128 + tid] + colL[256 + tid] + colL[384 + tid];

    // ---- phase 6: Q16 + QT16 (blk 0 only) ----
    if (blk == 0) {
        #pragma unroll
        for (int k = 0; k < 8; ++k) {
            int idx = tid + k * 256;
            int j = idx >> 4, h = idx & 15;
            *(short8_t*)&Q16[((size_t)(b * Lq + j)) * Dd + h * 8] =
                *(short8_t*)&Bbuf[j * AS + h * 8];
        }
        #pragma unroll
        for (int k = 0; k < 16; ++k) {
            int idx = tid + k * 256;
            int d = idx >> 5, j4 = idx & 31;
            short4_t o;
            #pragma unroll
            for (int r = 0; r < 4; ++r) {
                int j = j4 * 4 + r;
                o[r] = (qmL[j] != 0.f) ? Bbuf[j * AS + d] : (short)0;
            }
            *(short4_t*)&QT16[((size_t)(b * Dd + d)) * Lq + j4 * 4] = o;
        }
    }
}

// ================== k2: recompute E^T tiles, T = S2^T @ C -> TT16 [b,d,j] ==================
// 512 threads (2 waves/SIMD), register-double-buffered staging of CW/CT chunks.
__global__ __launch_bounds__(512) void k2_T(
    const short* __restrict__ CW16, const short* __restrict__ CT16,
    const short* __restrict__ Q16, const float* __restrict__ s0f,
    const float* __restrict__ s1f, const float* __restrict__ bias,
    const int* __restrict__ Qmask, const float* __restrict__ colpart,
    short* __restrict__ TT16)
{
    __shared__ short Qs[32 * AS];      // Q rows for this jq (32 x 128)
    __shared__ short CWs[64 * AS];     // Cw chunk rows (64 x 128); reused as Tb at end
    __shared__ short CTs[128 * CTS];   // masked C^T chunk (128 d x 64 i)
    __shared__ short Ps[32 * PS];      // P^T tile (32 j x 64 i)
    __shared__ float s1bL[32], invqL[32], s0L[64];

    int n = blockIdx.x;
    int b, jq; decode_bid(n, b, jq);   // jq in 0..3 (32 j's each)
    int tid = threadIdx.x, w = tid >> 6, lane = tid & 63;
    int lm = lane & 15, quad = lane >> 4;
    int jh = w & 1, ih = w >> 1;       // S phase: (jh,ih) tile; T phase: (jh, dgrp=ih)

    // stage Qs (32 j x 128 d): one short8 per thread
    {
        int j = tid >> 4, h = tid & 15;
        *(short8_t*)&Qs[j * AS + h * 8] =
            *(const short8_t*)&Q16[((size_t)(b * Lq + jq * 32 + j)) * Dd + h * 8];
    }
    if (tid < 32) {
        int j = jq * 32 + tid;
        s1bL[tid] = s1f[b * Lq + j] + bias[0];
        float cs = 0.f;
        #pragma unroll
        for (int p = 0; p < 16; ++p) cs += colpart[((size_t)b * 16 + p) * Lq + j];
        invqL[tid] = (Qmask[b * Lq + j] != 0) ? 1.0f / cs : 0.0f;
    }

    const short* CWb = CW16 + (size_t)b * Lc * Dd;
    const short* CTb = CT16 + (size_t)b * Dd * Lc;
    int iA0 = tid >> 4, iA1 = 32 + (tid >> 4), hA0 = (tid & 15) * 8;
    int dB0 = tid >> 3, dB1 = 64 + (tid >> 3), hB0 = (tid & 7) * 8;

    // prefetch chunk 0 into registers
    short8_t wA0 = *(const short8_t*)&CWb[(size_t)iA0 * Dd + hA0];
    short8_t wA1 = *(const short8_t*)&CWb[(size_t)iA1 * Dd + hA0];
    short8_t wB0 = *(const short8_t*)&CTb[(size_t)dB0 * Lc + hB0];
    short8_t wB1 = *(const short8_t*)&CTb[(size_t)dB1 * Lc + hB0];
    float s0r = (tid < 64) ? s0f[b * Lc + tid] : 0.f;

    f32x4 acc2[2];
    acc2[0] = (f32x4){0.f,0.f,0.f,0.f};
    acc2[1] = (f32x4){0.f,0.f,0.f,0.f};

    for (int ic = 0; ic < 16; ++ic) {
        __syncthreads();   // prev T-mfma done: CWs/CTs/s0L free
        *(short8_t*)&CWs[iA0 * AS + hA0] = wA0;
        *(short8_t*)&CWs[iA1 * AS + hA0] = wA1;
        *(short8_t*)&CTs[dB0 * CTS + hB0] = wB0;
        *(short8_t*)&CTs[dB1 * CTS + hB0] = wB1;
        if (tid < 64) s0L[tid] = s0r;
        if (ic < 15) {   // issue next chunk's loads; latency hides under MFMA phases
            int ibn = (ic + 1) * 64;
            wA0 = *(const short8_t*)&CWb[((size_t)(ibn + iA0)) * Dd + hA0];
            wA1 = *(const short8_t*)&CWb[((size_t)(ibn + iA1)) * Dd + hA0];
            wB0 = *(const short8_t*)&CTb[(size_t)dB0 * Lc + ibn + hB0];
            wB1 = *(const short8_t*)&CTb[(size_t)dB1 * Lc + ibn + hB0];
            if (tid < 64) s0r = s0f[b * Lc + ibn + tid];
        }
        __syncthreads();

        // S^T tile [16j x 16i]: a = Q rows (m=j), b = Cw rows (n=i). Bit-identical to k1's S.
        f32x4 sacc = (f32x4){0.f,0.f,0.f,0.f};
        #pragma unroll
        for (int ks = 0; ks < 4; ++ks) {
            short8_t a = *(short8_t*)&Qs[(jh * 16 + lm) * AS + ks * 32 + quad * 8];
            short8_t bf = *(short8_t*)&CWs[(ih * 16 + lm) * AS + ks * 32 + quad * 8];
            sacc = __builtin_amdgcn_mfma_f32_16x16x32_bf16(a, bf, sacc, 0, 0, 0);
        }
        float s0v = s0L[ih * 16 + lm];
        #pragma unroll
        for (int r = 0; r < 4; ++r) {
            float e = __expf(sacc[r] + s0v + s1bL[jh * 16 + quad * 4 + r]);
            Ps[(jh * 16 + quad * 4 + r) * PS + ih * 16 + lm] = f2bf(e);
        }
        __syncthreads();

        // T partial: [16j x 32d] per wave, k = 64 i
        #pragma unroll
        for (int ks = 0; ks < 2; ++ks) {
            short8_t a = *(short8_t*)&Ps[(jh * 16 + lm) * PS + ks * 32 + quad * 8];
            #pragma unroll
            for (int t = 0; t < 2; ++t) {
                short8_t bf = *(short8_t*)&CTs[((ih * 2 + t) * 16 + lm) * CTS + ks * 32 + quad * 8];
                acc2[t] = __builtin_amdgcn_mfma_f32_16x16x32_bf16(a, bf, acc2[t], 0, 0, 0);
            }
        }
    }

    // epilogue: scale by invq, transpose via LDS, coalesced TT16 write
    short* Tb = CWs;   // safe: CWs reads all completed before last T phase started
    #pragma unroll
    for (int t = 0; t < 2; ++t) {
        int d = (ih * 2 + t) * 16 + lm;
        #pragma unroll
        for (int r = 0; r < 4; ++r) {
            int jl = jh * 16 + quad * 4 + r;
            Tb[d * TBS + jl] = f2bf(acc2[t][r] * invqL[jl]);
        }
    }
    __syncthreads();
    #pragma unroll
    for (int k = 0; k < 2; ++k) {
        int idx = tid + k * 512;
        int d = idx >> 3, j4 = idx & 7;
        *(short4_t*)&TT16[((size_t)(b * Dd + d)) * Lq + jq * 32 + j4 * 4] =
            *(short4_t*)&Tb[d * TBS + j4 * 4];
    }
}

// ================== k3: recompute P=exp(S); A=(P@Qm)*rs, Bm=(P@T)*rs; out=[C,A,C*A,C*Bm] ==================
__global__ __launch_bounds__(256) void k3_out(
    const short* __restrict__ Q16, const short* __restrict__ QT16,
    const short* __restrict__ TT16, const float* __restrict__ C,
    const float* __restrict__ w_mul, const float* __restrict__ s0f,
    const float* __restrict__ s1f, const float* __restrict__ bias,
    const float* __restrict__ rowsumInv, float* __restrict__ out)
{
    __shared__ short Abuf[64 * AS];    // cw, then P (e bf16)
    __shared__ short Bbuf[128 * AS];   // Q, then QTs, then TTs, then f32 epilogue overlay
    __shared__ float s0L[64], s1bL[128];
    float* Af32 = (float*)Bbuf;        // 64*AS f32 = 33792 B = exactly Bbuf

    int n = blockIdx.x;
    int b, blk; decode_bid(n, b, blk);
    int i0 = blk * 64, tid = threadIdx.x;
    int w = tid >> 6, lane = tid & 63, lm = lane & 15, quad = lane >> 4;
    int iw = i0 + w * 16;

    // ---- stage Q16 -> Bbuf; C -> cv regs + cw -> Abuf ----
    const short8_t* Qg = (const short8_t*)(Q16 + (size_t)b * Lq * Dd);
    #pragma unroll
    for (int k = 0; k < 8; ++k) {
        int idx = tid + k * 256;
        int j = idx >> 4, h = idx & 15;
        *(short8_t*)&Bbuf[j * AS + h * 8] = Qg[idx];
    }
    const float4* C4 = (const float4*)(C + ((size_t)(b * Lc + i0)) * Dd);
    float4 cv[8];
    #pragma unroll
    for (int k = 0; k < 8; ++k) {
        int idx = tid + k * 256;
        int i = idx >> 5, d4 = idx & 31;
        float4 v = C4[idx];
        cv[k] = v;
        float4 wm = ((const float4*)w_mul)[d4];
        short4_t cw; cw[0]=f2bf(v.x*wm.x); cw[1]=f2bf(v.y*wm.y); cw[2]=f2bf(v.z*wm.z); cw[3]=f2bf(v.w*wm.w);
        *(short4_t*)&Abuf[i * AS + d4 * 4] = cw;
    }
    if (tid < 64) s0L[tid] = s0f[b * Lc + i0 + tid];
    if (tid >= 128 && tid < 256) s1bL[tid - 128] = s1f[b * Lq + tid - 128] + bias[0];
    __syncthreads();

    // ---- S = Cw @ Q^T (bit-identical to k1) ----
    f32x4 acc[8];
    #pragma unroll
    for (int t = 0; t < 8; ++t) acc[t] = (f32x4){0.f,0.f,0.f,0.f};
    #pragma unroll
    for (int ks = 0; ks < 4; ++ks) {
        short8_t a = *(short8_t*)&Abuf[(w * 16 + lm) * AS + ks * 32 + quad * 8];
        #pragma unroll
        for (int jt = 0; jt < 8; ++jt) {
            short8_t bf = *(short8_t*)&Bbuf[(jt * 16 + lm) * AS + ks * 32 + quad * 8];
            acc[jt] = __builtin_amdgcn_mfma_f32_16x16x32_bf16(a, bf, acc[jt], 0, 0, 0);
        }
    }
    // ---- P = exp(S) bf16 -> Abuf (own wave band; conflict-free quad layout) ----
    float s0v[4];
    #pragma unroll
    for (int r = 0; r < 4; ++r) s0v[r] = s0L[w * 16 + quad * 4 + r];
    #pragma unroll
    for (int jt = 0; jt < 8; ++jt) {
        int j = jt * 16 + lm;
        float s1b = s1bL[j];
        #pragma unroll
        for (int r = 0; r < 4; ++r) {
            float e = __expf(acc[jt][r] + s0v[r] + s1b);
            Abuf[(w * 16 + quad * 4 + r) * AS + j] = f2bf(e);
        }
    }
    __syncthreads();

    // ---- stage QTs -> Bbuf; accQ = P @ QT ----
    const short8_t* QTg = (const short8_t*)(QT16 + (size_t)b * Dd * Lq);
    #pragma unroll
    for (int k = 0; k < 8; ++k) {
        int idx = tid + k * 256;
        int d = idx >> 4, h = idx & 15;
        *(short8_t*)&Bbuf[d * AS + h * 8] = QTg[idx];
    }
    float rs[4];
    #pragma unroll
    for (int r = 0; r < 4; ++r) rs[r] = rowsumInv[b * Lc + iw + quad * 4 + r];
    __syncthreads();
    f32x4 accQ[8];
    #pragma unroll
    for (int t = 0; t < 8; ++t) accQ[t] = (f32x4){0.f,0.f,0.f,0.f};
    #pragma unroll
    for (int ks = 0; ks < 4; ++ks) {
        short8_t a = *(short8_t*)&Abuf[(w * 16 + lm) * AS + ks * 32 + quad * 8];
        #pragma unroll
        for (int dt = 0; dt < 8; ++dt) {
            short8_t bf = *(short8_t*)&Bbuf[(dt * 16 + lm) * AS + ks * 32 + quad * 8];
            accQ[dt] = __builtin_amdgcn_mfma_f32_16x16x32_bf16(a, bf, accQ[dt], 0, 0, 0);
        }
    }
    __syncthreads();

    // ---- stage TTs -> Bbuf; accT = P @ TT ----
    const short8_t* TTg = (const short8_t*)(TT16 + (size_t)b * Dd * Lq);
    #pragma unroll
    for (int k = 0; k < 8; ++k) {
        int idx = tid + k * 256;
        int d = idx >> 4, h = idx & 15;
        *(short8_t*)&Bbuf[d * AS + h * 8] = TTg[idx];
    }
    __syncthreads();
    f32x4 accT[8];
    #pragma unroll
    for (int t = 0; t < 8; ++t) accT[t] = (f32x4){0.f,0.f,0.f,0.f};
    #pragma unroll
    for (int ks = 0; ks < 4; ++ks) {
        short8_t a = *(short8_t*)&Abuf[(w * 16 + lm) * AS + ks * 32 + quad * 8];
        #pragma unroll
        for (int dt = 0; dt < 8; ++dt) {
            short8_t bf = *(short8_t*)&Bbuf[(dt * 16 + lm) * AS + ks * 32 + quad * 8];
            accT[dt] = __builtin_amdgcn_mfma_f32_16x16x32_bf16(a, bf, accT[dt], 0, 0, 0);
        }
    }
    __syncthreads();

    // ---- epilogue phase A: A -> LDS f32, float4 stores of C, A, C*A ----
    #pragma unroll
    for (int dt = 0; dt < 8; ++dt)
        #pragma unroll
        for (int r = 0; r < 4; ++r)
            Af32[(w * 16 + quad * 4 + r) * AS + dt * 16 + lm] = accQ[dt][r] * rs[r];
    __syncthreads();

    #pragma unroll
    for (int k = 0; k < 8; ++k) {
        int idx = tid + k * 256;
        int i = idx >> 5, d4 = idx & 31;
        float4 av = *(float4*)&Af32[i * AS + d4 * 4];
        float4 c = cv[k];
        size_t base = ((size_t)(b * Lc + i0 + i)) * (4 * Dd) + d4 * 4;
        *(float4*)&out[base]           = c;
        *(float4*)&out[base + Dd]      = av;
        float4 ca; ca.x = c.x*av.x; ca.y = c.y*av.y; ca.z = c.z*av.z; ca.w = c.w*av.w;
        *(float4*)&out[base + 2 * Dd]  = ca;
    }
    __syncthreads();

    // ---- epilogue phase B: Bm -> LDS f32, float4 stores of C*Bm ----
    #pragma unroll
    for (int dt = 0; dt < 8; ++dt)
        #pragma unroll
        for (int r = 0; r < 4; ++r)
            Af32[(w * 16 + quad * 4 + r) * AS + dt * 16 + lm] = accT[dt][r] * rs[r];
    __syncthreads();

    #pragma unroll
    for (int k = 0; k < 8; ++k) {
        int idx = tid + k * 256;
        int i = idx >> 5, d4 = idx & 31;
        float4 bm = *(float4*)&Af32[i * AS + d4 * 4];
        float4 c = cv[k];
        size_t base = ((size_t)(b * Lc + i0 + i)) * (4 * Dd) + d4 * 4;
        float4 cb; cb.x = c.x*bm.x; cb.y = c.y*bm.y; cb.z = c.z*bm.z; cb.w = c.w*bm.w;
        *(float4*)&out[base + 3 * Dd]  = cb;
    }
}

extern "C" void kernel_launch(void* const* d_in, const int* in_sizes, int n_in,
                              void* d_out, int out_size, void* d_ws, size_t ws_size,
                              hipStream_t stream) {
    const float* C     = (const float*)d_in[0];
    const float* Q     = (const float*)d_in[1];
    const int*   Cmask = (const int*)d_in[2];
    const int*   Qmask = (const int*)d_in[3];
    const float* w_c   = (const float*)d_in[4];
    const float* w_q   = (const float*)d_in[5];
    const float* w_mul = (const float*)d_in[6];
    const float* bias  = (const float*)d_in[7];
    float* out = (float*)d_out;

    char* p = (char*)d_ws;
    const size_t ND = (size_t)Bn * Lc * Dd;
    const size_t NQ = (size_t)Bn * Lq * Dd;
    short* CW16 = (short*)p; p += ND * 2;
    short* CT16 = (short*)p; p += ND * 2;
    short* Q16  = (short*)p; p += NQ * 2;
    short* QT16 = (short*)p; p += NQ * 2;
    short* TT16 = (short*)p; p += NQ * 2;
    float* s0f       = (float*)p; p += (size_t)Bn * Lc * 4;
    float* s1f       = (float*)p; p += (size_t)Bn * Lq * 4;
    float* colpart   = (float*)p; p += (size_t)Bn * 16 * Lq * 4;
    float* rowsumInv = (float*)p; p += (size_t)Bn * Lc * 4;

    k1_fused<<<dim3(1024), 256, 0, stream>>>(C, Q, Cmask, Qmask, w_c, w_q, w_mul, bias,
                                             CW16, CT16, Q16, QT16, s0f, s1f, colpart, rowsumInv);
    k2_T<<<dim3(256), 512, 0, stream>>>(CW16, CT16, Q16, s0f, s1f, bias, Qmask, colpart, TT16);
    k3_out<<<dim3(1024), 256, 0, stream>>>(Q16, QT16, TT16, C, w_mul, s0f, s1f, bias, rowsumInv, out);
}

// Round 2
// 246.953 us; speedup vs baseline: 1.1145x; 1.0082x over previous
//
#include <hip/hip_runtime.h>
#include <math.h>

constexpr int Bn = 64, Lc = 1024, Lq = 128, Dd = 128;

typedef __attribute__((ext_vector_type(8))) short short8_t;  // 8 bf16
typedef __attribute__((ext_vector_type(4))) short short4_t;  // 4 bf16
typedef __attribute__((ext_vector_type(4))) float f32x4;

__device__ __forceinline__ short f2bf(float x) {
    unsigned u = __float_as_uint(x);
    u += 0x7FFFu + ((u >> 16) & 1u);   // round-to-nearest-even
    return (short)(u >> 16);
}

constexpr int AS = 132;   // [row][d] LDS stride (shorts)
constexpr int TS = 70;    // k1 transpose buf stride
constexpr int CTS = 68;   // k2 CT staging stride (shorts)
constexpr int PS = 68;    // k2 P^T tile stride (shorts)
constexpr int TBS = 36;   // k2 out-transpose stride (shorts)

// XCD swizzle: same-b blocks share n%8 -> same XCD under round-robin dispatch.
__device__ __forceinline__ void decode_bid(int n, int& b, int& blk) {
    b = (n & 7) * 8 + ((n >> 3) & 7);
    blk = n >> 6;
}

// ================== k1: prep tiles + S + sums. 51 KB LDS -> 3 blocks/CU ==================
__global__ __launch_bounds__(256, 3) void k1_fused(
    const float* __restrict__ C, const float* __restrict__ Q,
    const int* __restrict__ Cmask, const int* __restrict__ Qmask,
    const float* __restrict__ w_c, const float* __restrict__ w_q,
    const float* __restrict__ w_mul, const float* __restrict__ bias,
    short* __restrict__ CT16,
    short* __restrict__ Q16, short* __restrict__ QT16,
    float* __restrict__ s0f, float* __restrict__ s1f,
    float* __restrict__ colpart, float* __restrict__ rowsumInv)
{
    __shared__ short Abuf[64 * AS];    // C*w_mul bf16, [i][d]
    __shared__ short Bbuf[128 * AS];   // Q bf16, [j][d]; first 128*TS doubles as Tbuf; colL overlay at end
    __shared__ float s0L[64], cmL[64], s1L[128], qmL[128];
    short* Tbuf = Bbuf;

    int b, blk; decode_bid(blockIdx.x, b, blk);
    int i0 = blk * 64, tid = threadIdx.x;

    // ---- phase 1: C tile -> Abuf (cw), Tbuf (cm*C, [d][i]), s0, cm ----
    const float4* C4 = (const float4*)(C + ((size_t)(b * Lc + i0)) * Dd);
    #pragma unroll
    for (int k = 0; k < 8; ++k) {
        int idx = tid + k * 256;
        int i = idx >> 5, d4 = idx & 31;
        float4 v = C4[idx];
        float4 wm = ((const float4*)w_mul)[d4];
        short4_t cw; cw[0]=f2bf(v.x*wm.x); cw[1]=f2bf(v.y*wm.y); cw[2]=f2bf(v.z*wm.z); cw[3]=f2bf(v.w*wm.w);
        *(short4_t*)&Abuf[i * AS + d4 * 4] = cw;
        float cm = (Cmask[b * Lc + i0 + i] != 0) ? 1.0f : 0.0f;
        Tbuf[(d4*4+0)*TS + i] = f2bf(cm * v.x);
        Tbuf[(d4*4+1)*TS + i] = f2bf(cm * v.y);
        Tbuf[(d4*4+2)*TS + i] = f2bf(cm * v.z);
        Tbuf[(d4*4+3)*TS + i] = f2bf(cm * v.w);
        float4 wc = ((const float4*)w_c)[d4];
        float dot = v.x*wc.x + v.y*wc.y + v.z*wc.z + v.w*wc.w;
        #pragma unroll
        for (int off = 1; off < 32; off <<= 1) dot += __shfl_xor(dot, off, 64);
        if ((tid & 31) == 0) { s0L[i] = dot; cmL[i] = cm; s0f[b * Lc + i0 + i] = dot; }
    }
    __syncthreads();

    // ---- phase 2: CT16 out (masked C^T, bf16) ----
    #pragma unroll
    for (int k = 0; k < 8; ++k) {
        int idx = tid + k * 256;
        int d = idx >> 4, i4 = idx & 15;
        *(short4_t*)&CT16[((size_t)(b * Dd + d)) * Lc + i0 + i4 * 4] =
            *(short4_t*)&Tbuf[d * TS + i4 * 4];
    }
    __syncthreads();

    // ---- phase 3: Q -> Bbuf, s1, qm ----
    const float4* Q4 = (const float4*)(Q + (size_t)b * Lq * Dd);
    #pragma unroll
    for (int k = 0; k < 16; ++k) {
        int idx = tid + k * 256;
        int j = idx >> 5, d4 = idx & 31;
        float4 v = Q4[idx];
        short4_t qv; qv[0]=f2bf(v.x); qv[1]=f2bf(v.y); qv[2]=f2bf(v.z); qv[3]=f2bf(v.w);
        *(short4_t*)&Bbuf[j * AS + d4 * 4] = qv;
        float4 wq = ((const float4*)w_q)[d4];
        float dot = v.x*wq.x + v.y*wq.y + v.z*wq.z + v.w*wq.w;
        #pragma unroll
        for (int off = 1; off < 32; off <<= 1) dot += __shfl_xor(dot, off, 64);
        if ((tid & 31) == 0) {
            s1L[j] = dot;
            qmL[j] = (Qmask[b * Lq + j] != 0) ? 1.0f : 0.0f;
            if (blk == 0) s1f[b * Lq + j] = dot;
        }
    }
    __syncthreads();

    // ---- phase 4: MFMA S = Cw @ Q^T ----
    int w = tid >> 6, lane = tid & 63, lm = lane & 15, quad = lane >> 4;
    int iw = i0 + w * 16;
    f32x4 acc[8];
    #pragma unroll
    for (int t = 0; t < 8; ++t) acc[t] = (f32x4){0.f,0.f,0.f,0.f};
    #pragma unroll
    for (int ks = 0; ks < 4; ++ks) {
        short8_t a = *(short8_t*)&Abuf[(w * 16 + lm) * AS + ks * 32 + quad * 8];
        #pragma unroll
        for (int jt = 0; jt < 8; ++jt) {
            short8_t bf = *(short8_t*)&Bbuf[(jt * 16 + lm) * AS + ks * 32 + quad * 8];
            acc[jt] = __builtin_amdgcn_mfma_f32_16x16x32_bf16(a, bf, acc[jt], 0, 0, 0);
        }
    }

    // ---- phase 6 (moved before 5): Q16 + QT16 (blk 0 only; reads Bbuf) ----
    if (blk == 0) {
        #pragma unroll
        for (int k = 0; k < 8; ++k) {
            int idx = tid + k * 256;
            int j = idx >> 4, h = idx & 15;
            *(short8_t*)&Q16[((size_t)(b * Lq + j)) * Dd + h * 8] =
                *(short8_t*)&Bbuf[j * AS + h * 8];
        }
        #pragma unroll
        for (int k = 0; k < 16; ++k) {
            int idx = tid + k * 256;
            int d = idx >> 5, j4 = idx & 31;
            short4_t o;
            #pragma unroll
            for (int r = 0; r < 4; ++r) {
                int j = j4 * 4 + r;
                o[r] = (qmL[j] != 0.f) ? Bbuf[j * AS + d] : (short)0;
            }
            *(short4_t*)&QT16[((size_t)(b * Dd + d)) * Lq + j4 * 4] = o;
        }
    }
    __syncthreads();   // all Bbuf reads done; colL overlay becomes safe

    // ---- phase 5: exp + rowsumInv + col partials (colL overlaid on Bbuf) ----
    float* colL = (float*)Bbuf;        // 512 floats
    float s0v[4], cmv[4];
    #pragma unroll
    for (int r = 0; r < 4; ++r) {
        s0v[r] = s0L[w * 16 + quad * 4 + r];
        cmv[r] = cmL[w * 16 + quad * 4 + r];
    }
    float bb = bias[0];
    float rowpart[4] = {0.f, 0.f, 0.f, 0.f};
    #pragma unroll
    for (int jt = 0; jt < 8; ++jt) {
        int j = jt * 16 + lm;
        float s1 = s1L[j] + bb;
        float qm = qmL[j];
        float cs = 0.f;
        #pragma unroll
        for (int r = 0; r < 4; ++r) {
            float e = __expf(acc[jt][r] + s0v[r] + s1);
            rowpart[r] += qm * e;
            cs += cmv[r] * e;
        }
        cs += __shfl_xor(cs, 16, 64);
        cs += __shfl_xor(cs, 32, 64);
        if (lane < 16) colL[w * 128 + j] = cs;
    }
    #pragma unroll
    for (int r = 0; r < 4; ++r) {
        float v = rowpart[r];
        v += __shfl_xor(v, 1, 64); v += __shfl_xor(v, 2, 64);
        v += __shfl_xor(v, 4, 64); v += __shfl_xor(v, 8, 64);
        if (lm == 0) rowsumInv[b * Lc + iw + quad * 4 + r] = 1.0f / v;
    }
    __syncthreads();
    if (tid < 128)
        colpart[((size_t)b * 16 + blk) * Lq + tid] =
            colL[tid] + colL[128 + tid] + colL[256 + tid] + colL[384 + tid];
}

// ================== k2: recompute E^T tiles (Cw rebuilt from C f32), T = S2^T @ C ==================
__global__ __launch_bounds__(512) void k2_T(
    const float* __restrict__ C, const short* __restrict__ CT16,
    const short* __restrict__ Q16, const float* __restrict__ s0f,
    const float* __restrict__ s1f, const float* __restrict__ bias,
    const float* __restrict__ w_mul,
    const int* __restrict__ Qmask, const float* __restrict__ colpart,
    short* __restrict__ TT16)
{
    __shared__ short Qs[32 * AS];      // Q rows for this jq (32 x 128)
    __shared__ short CWs[64 * AS];     // Cw chunk rows (64 x 128); reused as Tb at end
    __shared__ short CTs[128 * CTS];   // masked C^T chunk (128 d x 64 i)
    __shared__ short Ps[32 * PS];      // P^T tile (32 j x 64 i)
    __shared__ float s1bL[32], invqL[32], s0L[64];

    int n = blockIdx.x;
    int b, jq; decode_bid(n, b, jq);   // jq in 0..3 (32 j's each)
    int tid = threadIdx.x, w = tid >> 6, lane = tid & 63;
    int lm = lane & 15, quad = lane >> 4;
    int jh = w & 1, ih = w >> 1;       // S phase: (jh,ih) tile; T phase: (jh, dgrp=ih)

    // stage Qs (32 j x 128 d): one short8 per thread
    {
        int j = tid >> 4, h = tid & 15;
        *(short8_t*)&Qs[j * AS + h * 8] =
            *(const short8_t*)&Q16[((size_t)(b * Lq + jq * 32 + j)) * Dd + h * 8];
    }
    if (tid < 32) {
        int j = jq * 32 + tid;
        s1bL[tid] = s1f[b * Lq + j] + bias[0];
        float cs = 0.f;
        #pragma unroll
        for (int p = 0; p < 16; ++p) cs += colpart[((size_t)b * 16 + p) * Lq + j];
        invqL[tid] = (Qmask[b * Lq + j] != 0) ? 1.0f / cs : 0.0f;
    }

    const float4* Cb4 = (const float4*)(C + (size_t)b * Lc * Dd);
    const short* CTb = CT16 + (size_t)b * Dd * Lc;
    int iS = tid >> 5, dS = tid & 31;          // C staging: i-base (0..15), d4 (fixed)
    int dB0 = tid >> 3, dB1 = 64 + (tid >> 3), hB0 = (tid & 7) * 8;
    float4 wmv = ((const float4*)w_mul)[dS];

    // prefetch chunk 0 into registers
    float4 pc[4];
    #pragma unroll
    for (int k = 0; k < 4; ++k)
        pc[k] = Cb4[((size_t)(iS + k * 16)) * 32 + dS];
    short8_t wB0 = *(const short8_t*)&CTb[(size_t)dB0 * Lc + hB0];
    short8_t wB1 = *(const short8_t*)&CTb[(size_t)dB1 * Lc + hB0];
    float s0r = (tid < 64) ? s0f[b * Lc + tid] : 0.f;

    f32x4 acc2[2];
    acc2[0] = (f32x4){0.f,0.f,0.f,0.f};
    acc2[1] = (f32x4){0.f,0.f,0.f,0.f};

    for (int ic = 0; ic < 16; ++ic) {
        __syncthreads();   // prev T-mfma done: CWs/CTs/s0L free
        #pragma unroll
        for (int k = 0; k < 4; ++k) {
            float4 v = pc[k];
            short4_t cw;
            cw[0]=f2bf(v.x*wmv.x); cw[1]=f2bf(v.y*wmv.y); cw[2]=f2bf(v.z*wmv.z); cw[3]=f2bf(v.w*wmv.w);
            *(short4_t*)&CWs[(iS + k * 16) * AS + dS * 4] = cw;
        }
        *(short8_t*)&CTs[dB0 * CTS + hB0] = wB0;
        *(short8_t*)&CTs[dB1 * CTS + hB0] = wB1;
        if (tid < 64) s0L[tid] = s0r;
        if (ic < 15) {   // issue next chunk's loads; latency hides under MFMA phases
            int ibn = (ic + 1) * 64;
            #pragma unroll
            for (int k = 0; k < 4; ++k)
                pc[k] = Cb4[((size_t)(ibn + iS + k * 16)) * 32 + dS];
            wB0 = *(const short8_t*)&CTb[(size_t)dB0 * Lc + ibn + hB0];
            wB1 = *(const short8_t*)&CTb[(size_t)dB1 * Lc + ibn + hB0];
            if (tid < 64) s0r = s0f[b * Lc + ibn + tid];
        }
        __syncthreads();

        // S^T tile [16j x 16i]: a = Q rows (m=j), b = Cw rows (n=i). Bit-identical to k3's S.
        f32x4 sacc = (f32x4){0.f,0.f,0.f,0.f};
        #pragma unroll
        for (int ks = 0; ks < 4; ++ks) {
            short8_t a = *(short8_t*)&Qs[(jh * 16 + lm) * AS + ks * 32 + quad * 8];
            short8_t bf = *(short8_t*)&CWs[(ih * 16 + lm) * AS + ks * 32 + quad * 8];
            sacc = __builtin_amdgcn_mfma_f32_16x16x32_bf16(a, bf, sacc, 0, 0, 0);
        }
        float s0v = s0L[ih * 16 + lm];
        #pragma unroll
        for (int r = 0; r < 4; ++r) {
            float e = __expf(sacc[r] + s0v + s1bL[jh * 16 + quad * 4 + r]);
            Ps[(jh * 16 + quad * 4 + r) * PS + ih * 16 + lm] = f2bf(e);
        }
        __syncthreads();

        // T partial: [16j x 32d] per wave, k = 64 i
        #pragma unroll
        for (int ks = 0; ks < 2; ++ks) {
            short8_t a = *(short8_t*)&Ps[(jh * 16 + lm) * PS + ks * 32 + quad * 8];
            #pragma unroll
            for (int t = 0; t < 2; ++t) {
                short8_t bf = *(short8_t*)&CTs[((ih * 2 + t) * 16 + lm) * CTS + ks * 32 + quad * 8];
                acc2[t] = __builtin_amdgcn_mfma_f32_16x16x32_bf16(a, bf, acc2[t], 0, 0, 0);
            }
        }
    }

    // epilogue: scale by invq, transpose via LDS, coalesced TT16 write
    short* Tb = CWs;   // safe: CWs reads all completed before last T phase started
    #pragma unroll
    for (int t = 0; t < 2; ++t) {
        int d = (ih * 2 + t) * 16 + lm;
        #pragma unroll
        for (int r = 0; r < 4; ++r) {
            int jl = jh * 16 + quad * 4 + r;
            Tb[d * TBS + jl] = f2bf(acc2[t][r] * invqL[jl]);
        }
    }
    __syncthreads();
    #pragma unroll
    for (int k = 0; k < 2; ++k) {
        int idx = tid + k * 512;
        int d = idx >> 3, j4 = idx & 7;
        *(short4_t*)&TT16[((size_t)(b * Dd + d)) * Lq + jq * 32 + j4 * 4] =
            *(short4_t*)&Tb[d * TBS + j4 * 4];
    }
}

// ================== k3: recompute P=exp(S); A=(P@Qm)*rs then Bm=(P@T)*rs serialized ==================
__global__ __launch_bounds__(256, 3) void k3_out(
    const short* __restrict__ Q16, const short* __restrict__ QT16,
    const short* __restrict__ TT16, const float* __restrict__ C,
    const float* __restrict__ w_mul, const float* __restrict__ s0f,
    const float* __restrict__ s1f, const float* __restrict__ bias,
    const float* __restrict__ rowsumInv, float* __restrict__ out)
{
    __shared__ short Abuf[64 * AS];    // cw, then P (e bf16)
    __shared__ short Bbuf[128 * AS];   // Q -> QTs -> Af32 -> TTs -> Af32
    __shared__ float s0L[64], s1bL[128];
    float* Af32 = (float*)Bbuf;        // 64*AS f32 = 33792 B = exactly Bbuf

    int n = blockIdx.x;
    int b, blk; decode_bid(n, b, blk);
    int i0 = blk * 64, tid = threadIdx.x;
    int w = tid >> 6, lane = tid & 63, lm = lane & 15, quad = lane >> 4;
    int iw = i0 + w * 16;

    // ---- stage Q16 -> Bbuf; C -> cw -> Abuf (no register C copy) ----
    const short8_t* Qg = (const short8_t*)(Q16 + (size_t)b * Lq * Dd);
    #pragma unroll
    for (int k = 0; k < 8; ++k) {
        int idx = tid + k * 256;
        int j = idx >> 4, h = idx & 15;
        *(short8_t*)&Bbuf[j * AS + h * 8] = Qg[idx];
    }
    const float4* C4 = (const float4*)(C + ((size_t)(b * Lc + i0)) * Dd);
    #pragma unroll
    for (int k = 0; k < 8; ++k) {
        int idx = tid + k * 256;
        int i = idx >> 5, d4 = idx & 31;
        float4 v = C4[idx];
        float4 wm = ((const float4*)w_mul)[d4];
        short4_t cw; cw[0]=f2bf(v.x*wm.x); cw[1]=f2bf(v.y*wm.y); cw[2]=f2bf(v.z*wm.z); cw[3]=f2bf(v.w*wm.w);
        *(short4_t*)&Abuf[i * AS + d4 * 4] = cw;
    }
    if (tid < 64) s0L[tid] = s0f[b * Lc + i0 + tid];
    if (tid >= 128 && tid < 256) s1bL[tid - 128] = s1f[b * Lq + tid - 128] + bias[0];
    __syncthreads();

    // ---- S = Cw @ Q^T (bit-identical to k2's S^T) ----
    f32x4 acc[8];
    #pragma unroll
    for (int t = 0; t < 8; ++t) acc[t] = (f32x4){0.f,0.f,0.f,0.f};
    #pragma unroll
    for (int ks = 0; ks < 4; ++ks) {
        short8_t a = *(short8_t*)&Abuf[(w * 16 + lm) * AS + ks * 32 + quad * 8];
        #pragma unroll
        for (int jt = 0; jt < 8; ++jt) {
            short8_t bf = *(short8_t*)&Bbuf[(jt * 16 + lm) * AS + ks * 32 + quad * 8];
            acc[jt] = __builtin_amdgcn_mfma_f32_16x16x32_bf16(a, bf, acc[jt], 0, 0, 0);
        }
    }
    // ---- P = exp(S) bf16 -> Abuf (own wave band; no sync needed) ----
    float s0v[4];
    #pragma unroll
    for (int r = 0; r < 4; ++r) s0v[r] = s0L[w * 16 + quad * 4 + r];
    #pragma unroll
    for (int jt = 0; jt < 8; ++jt) {
        int j = jt * 16 + lm;
        float s1b = s1bL[j];
        #pragma unroll
        for (int r = 0; r < 4; ++r) {
            float e = __expf(acc[jt][r] + s0v[r] + s1b);
            Abuf[(w * 16 + quad * 4 + r) * AS + j] = f2bf(e);
        }
    }
    __syncthreads();

    // ---- stage QTs -> Bbuf; accQ = P @ QT ----
    const short8_t* QTg = (const short8_t*)(QT16 + (size_t)b * Dd * Lq);
    #pragma unroll
    for (int k = 0; k < 8; ++k) {
        int idx = tid + k * 256;
        int d = idx >> 4, h = idx & 15;
        *(short8_t*)&Bbuf[d * AS + h * 8] = QTg[idx];
    }
    float rs[4];
    #pragma unroll
    for (int r = 0; r < 4; ++r) rs[r] = rowsumInv[b * Lc + iw + quad * 4 + r];
    __syncthreads();
    f32x4 accQ[8];
    #pragma unroll
    for (int t = 0; t < 8; ++t) accQ[t] = (f32x4){0.f,0.f,0.f,0.f};
    #pragma unroll
    for (int ks = 0; ks < 4; ++ks) {
        short8_t a = *(short8_t*)&Abuf[(w * 16 + lm) * AS + ks * 32 + quad * 8];
        #pragma unroll
        for (int dt = 0; dt < 8; ++dt) {
            short8_t bf = *(short8_t*)&Bbuf[(dt * 16 + lm) * AS + ks * 32 + quad * 8];
            accQ[dt] = __builtin_amdgcn_mfma_f32_16x16x32_bf16(a, bf, accQ[dt], 0, 0, 0);
        }
    }
    __syncthreads();

    // ---- epilogue A: Af32 = accQ*rs; stores of C, A, C*A (C reloaded from L2) ----
    #pragma unroll
    for (int dt = 0; dt < 8; ++dt)
        #pragma unroll
        for (int r = 0; r < 4; ++r)
            Af32[(w * 16 + quad * 4 + r) * AS + dt * 16 + lm] = accQ[dt][r] * rs[r];
    __syncthreads();

    #pragma unroll
    for (int k = 0; k < 8; ++k) {
        int idx = tid + k * 256;
        int i = idx >> 5, d4 = idx & 31;
        float4 av = *(float4*)&Af32[i * AS + d4 * 4];
        float4 c = C4[idx];
        size_t base = ((size_t)(b * Lc + i0 + i)) * (4 * Dd) + d4 * 4;
        *(float4*)&out[base]           = c;
        *(float4*)&out[base + Dd]      = av;
        float4 ca; ca.x = c.x*av.x; ca.y = c.y*av.y; ca.z = c.z*av.z; ca.w = c.w*av.w;
        *(float4*)&out[base + 2 * Dd]  = ca;
    }
    __syncthreads();

    // ---- stage TTs -> Bbuf; accT = P @ TT ----
    const short8_t* TTg = (const short8_t*)(TT16 + (size_t)b * Dd * Lq);
    #pragma unroll
    for (int k = 0; k < 8; ++k) {
        int idx = tid + k * 256;
        int d = idx >> 4, h = idx & 15;
        *(short8_t*)&Bbuf[d * AS + h * 8] = TTg[idx];
    }
    __syncthreads();
    f32x4 accT[8];
    #pragma unroll
    for (int t = 0; t < 8; ++t) accT[t] = (f32x4){0.f,0.f,0.f,0.f};
    #pragma unroll
    for (int ks = 0; ks < 4; ++ks) {
        short8_t a = *(short8_t*)&Abuf[(w * 16 + lm) * AS + ks * 32 + quad * 8];
        #pragma unroll
        for (int dt = 0; dt < 8; ++dt) {
            short8_t bf = *(short8_t*)&Bbuf[(dt * 16 + lm) * AS + ks * 32 + quad * 8];
            accT[dt] = __builtin_amdgcn_mfma_f32_16x16x32_bf16(a, bf, accT[dt], 0, 0, 0);
        }
    }
    __syncthreads();

    // ---- epilogue B: Af32 = accT*rs; store C*Bm ----
    #pragma unroll
    for (int dt = 0; dt < 8; ++dt)
        #pragma unroll
        for (int r = 0; r < 4; ++r)
            Af32[(w * 16 + quad * 4 + r) * AS + dt * 16 + lm] = accT[dt][r] * rs[r];
    __syncthreads();

    #pragma unroll
    for (int k = 0; k < 8; ++k) {
        int idx = tid + k * 256;
        int i = idx >> 5, d4 = idx & 31;
        float4 bm = *(float4*)&Af32[i * AS + d4 * 4];
        float4 c = C4[idx];
        size_t base = ((size_t)(b * Lc + i0 + i)) * (4 * Dd) + d4 * 4;
        float4 cb; cb.x = c.x*bm.x; cb.y = c.y*bm.y; cb.z = c.z*bm.z; cb.w = c.w*bm.w;
        *(float4*)&out[base + 3 * Dd]  = cb;
    }
}

extern "C" void kernel_launch(void* const* d_in, const int* in_sizes, int n_in,
                              void* d_out, int out_size, void* d_ws, size_t ws_size,
                              hipStream_t stream) {
    const float* C     = (const float*)d_in[0];
    const float* Q     = (const float*)d_in[1];
    const int*   Cmask = (const int*)d_in[2];
    const int*   Qmask = (const int*)d_in[3];
    const float* w_c   = (const float*)d_in[4];
    const float* w_q   = (const float*)d_in[5];
    const float* w_mul = (const float*)d_in[6];
    const float* bias  = (const float*)d_in[7];
    float* out = (float*)d_out;

    char* p = (char*)d_ws;
    const size_t ND = (size_t)Bn * Lc * Dd;
    const size_t NQ = (size_t)Bn * Lq * Dd;
    short* CT16 = (short*)p; p += ND * 2;
    short* Q16  = (short*)p; p += NQ * 2;
    short* QT16 = (short*)p; p += NQ * 2;
    short* TT16 = (short*)p; p += NQ * 2;
    float* s0f       = (float*)p; p += (size_t)Bn * Lc * 4;
    float* s1f       = (float*)p; p += (size_t)Bn * Lq * 4;
    float* colpart   = (float*)p; p += (size_t)Bn * 16 * Lq * 4;
    float* rowsumInv = (float*)p; p += (size_t)Bn * Lc * 4;

    k1_fused<<<dim3(1024), 256, 0, stream>>>(C, Q, Cmask, Qmask, w_c, w_q, w_mul, bias,
                                             CT16, Q16, QT16, s0f, s1f, colpart, rowsumInv);
    k2_T<<<dim3(256), 512, 0, stream>>>(C, CT16, Q16, s0f, s1f, bias, w_mul, Qmask, colpart, TT16);
    k3_out<<<dim3(1024), 256, 0, stream>>>(Q16, QT16, TT16, C, w_mul, s0f, s1f, bias, rowsumInv, out);
}

// Round 3
// 220.253 us; speedup vs baseline: 1.2497x; 1.1212x over previous
//
#include <hip/hip_runtime.h>
#include <math.h>

constexpr int Bn = 64, Lc = 1024, Lq = 128, Dd = 128;

typedef __attribute__((ext_vector_type(8))) short short8_t;  // 8 bf16
typedef __attribute__((ext_vector_type(4))) short short4_t;  // 4 bf16
typedef __attribute__((ext_vector_type(4))) float f32x4;

__device__ __forceinline__ short f2bf(float x) {
    unsigned u = __float_as_uint(x);
    u += 0x7FFFu + ((u >> 16) & 1u);   // round-to-nearest-even
    return (short)(u >> 16);
}

constexpr int AS = 132;   // [row][d] LDS stride (shorts)
constexpr int CTS = 68;   // kT C^T staging stride (shorts)
constexpr int PS = 68;    // kT P^T tile stride (shorts)
constexpr int TBS = 36;   // kT out-transpose stride (shorts)

// XCD swizzle: same-b blocks share n%8 -> same XCD under round-robin dispatch.
__device__ __forceinline__ void decode_bid(int n, int& b, int& blk) {
    b = (n & 7) * 8 + ((n >> 3) & 7);
    blk = n >> 6;
}

// ============ kT: Q prep/export + recompute E^T + T = S2^T @ C -> TT16; colsum internal ============
// grid (256) = (4 jq x 64 b), 512 threads. C staged from f32 with in-LDS transpose (no CT16 ws buf).
__global__ __launch_bounds__(512) void kT(
    const float* __restrict__ C, const float* __restrict__ Q,
    const int* __restrict__ Cmask, const int* __restrict__ Qmask,
    const float* __restrict__ w_c, const float* __restrict__ w_q,
    const float* __restrict__ w_mul, const float* __restrict__ bias,
    short* __restrict__ Q16, short* __restrict__ QT16,
    float* __restrict__ s1f, short* __restrict__ TT16)
{
    __shared__ short Qs[32 * AS];      // Q bf16 rows for this jq slice
    __shared__ short CWs[64 * AS];     // Cw chunk rows; reused as Tb at end
    __shared__ short CTs[128 * CTS];   // masked C^T chunk (128 d x 64 i)
    __shared__ short Ps[32 * PS];      // P^T tile (32 j x 64 i)
    __shared__ float s1bL[32], qmL[32], invqL[32], s0L[64], cmL[64];
    __shared__ float colAcc[4 * 32];

    int n = blockIdx.x;
    int b, jq; decode_bid(n, b, jq);   // jq in 0..3
    int tid = threadIdx.x, w = tid >> 6, lane = tid & 63;
    int lm = lane & 15, quad = lane >> 4;
    int jh = w & 1, ih = w >> 1;       // wave tile coords

    // ---- phase 0: Q f32 slice -> Qs bf16 + Q16 export + s1 + qm ----
    {
        int j = tid >> 4, d4 = tid & 15;
        const float4* Q4 = (const float4*)(Q + ((size_t)(b * Lq + jq * 32 + j)) * Dd);
        float4 v0 = Q4[d4], v1 = Q4[d4 + 16];
        short4_t q0, q1;
        q0[0]=f2bf(v0.x); q0[1]=f2bf(v0.y); q0[2]=f2bf(v0.z); q0[3]=f2bf(v0.w);
        q1[0]=f2bf(v1.x); q1[1]=f2bf(v1.y); q1[2]=f2bf(v1.z); q1[3]=f2bf(v1.w);
        *(short4_t*)&Qs[j * AS + d4 * 4] = q0;
        *(short4_t*)&Qs[j * AS + (d4 + 16) * 4] = q1;
        *(short4_t*)&Q16[((size_t)(b * Lq + jq * 32 + j)) * Dd + d4 * 4] = q0;
        *(short4_t*)&Q16[((size_t)(b * Lq + jq * 32 + j)) * Dd + (d4 + 16) * 4] = q1;
        float4 wq0 = ((const float4*)w_q)[d4], wq1 = ((const float4*)w_q)[d4 + 16];
        float dot = v0.x*wq0.x + v0.y*wq0.y + v0.z*wq0.z + v0.w*wq0.w
                  + v1.x*wq1.x + v1.y*wq1.y + v1.z*wq1.z + v1.w*wq1.w;
        #pragma unroll
        for (int off = 1; off < 16; off <<= 1) dot += __shfl_xor(dot, off, 64);
        if (d4 == 0) {
            s1bL[j] = dot + bias[0];
            s1f[b * Lq + jq * 32 + j] = dot;
            qmL[j] = (Qmask[b * Lq + jq * 32 + j] != 0) ? 1.0f : 0.0f;
        }
    }

    // ---- prefetch C chunk 0 into registers ----
    const float4* Cb4 = (const float4*)(C + (size_t)b * Lc * Dd);
    int iS = tid >> 5, dS = tid & 31;
    float4 wmv = ((const float4*)w_mul)[dS];
    float4 wcv = ((const float4*)w_c)[dS];
    float4 pc[4]; int pm[4];
    #pragma unroll
    for (int k = 0; k < 4; ++k) {
        pc[k] = Cb4[((size_t)(iS + k * 16)) * 32 + dS];
        pm[k] = Cmask[b * Lc + iS + k * 16];
    }

    float csum[4] = {0.f, 0.f, 0.f, 0.f};
    f32x4 acc2[2];
    acc2[0] = (f32x4){0.f,0.f,0.f,0.f};
    acc2[1] = (f32x4){0.f,0.f,0.f,0.f};

    for (int ic = 0; ic < 16; ++ic) {
        __syncthreads();   // prev S/T reads of CWs/CTs/s0L done (also covers phase-0 writes)
        #pragma unroll
        for (int k = 0; k < 4; ++k) {
            float4 v = pc[k];
            float cm = pm[k] ? 1.0f : 0.0f;
            int i = iS + k * 16;
            short4_t cw;
            cw[0]=f2bf(v.x*wmv.x); cw[1]=f2bf(v.y*wmv.y); cw[2]=f2bf(v.z*wmv.z); cw[3]=f2bf(v.w*wmv.w);
            *(short4_t*)&CWs[i * AS + dS * 4] = cw;
            CTs[(dS*4+0)*CTS + i] = f2bf(cm * v.x);
            CTs[(dS*4+1)*CTS + i] = f2bf(cm * v.y);
            CTs[(dS*4+2)*CTS + i] = f2bf(cm * v.z);
            CTs[(dS*4+3)*CTS + i] = f2bf(cm * v.w);
            float dot = v.x*wcv.x + v.y*wcv.y + v.z*wcv.z + v.w*wcv.w;
            #pragma unroll
            for (int off = 1; off < 32; off <<= 1) dot += __shfl_xor(dot, off, 64);
            if (dS == 0) { s0L[i] = dot; cmL[i] = cm; }
        }
        if (ic < 15) {   // prefetch next chunk; latency hides under MFMA phases
            int ibn = (ic + 1) * 64;
            #pragma unroll
            for (int k = 0; k < 4; ++k) {
                pc[k] = Cb4[((size_t)(ibn + iS + k * 16)) * 32 + dS];
                pm[k] = Cmask[b * Lc + ibn + iS + k * 16];
            }
        }
        __syncthreads();

        // S^T tile [32j x 64i] across 8 waves; bit-identical to k3's S (operand swap)
        f32x4 sacc = (f32x4){0.f,0.f,0.f,0.f};
        #pragma unroll
        for (int ks = 0; ks < 4; ++ks) {
            short8_t a = *(short8_t*)&Qs[(jh * 16 + lm) * AS + ks * 32 + quad * 8];
            short8_t bq = *(short8_t*)&CWs[(ih * 16 + lm) * AS + ks * 32 + quad * 8];
            sacc = __builtin_amdgcn_mfma_f32_16x16x32_bf16(a, bq, sacc, 0, 0, 0);
        }
        float s0v = s0L[ih * 16 + lm];
        float cmv = cmL[ih * 16 + lm];
        #pragma unroll
        for (int r = 0; r < 4; ++r) {
            float e = __expf(sacc[r] + s0v + s1bL[jh * 16 + quad * 4 + r]);
            Ps[(jh * 16 + quad * 4 + r) * PS + ih * 16 + lm] = f2bf(e);
            csum[r] += cmv * e;    // colsum accumulation in registers (f32 e, as before)
        }
        __syncthreads();

        // T partial: [16j x 32d] per wave, k = 64 i
        #pragma unroll
        for (int ks = 0; ks < 2; ++ks) {
            short8_t a = *(short8_t*)&Ps[(jh * 16 + lm) * PS + ks * 32 + quad * 8];
            #pragma unroll
            for (int t = 0; t < 2; ++t) {
                short8_t bf = *(short8_t*)&CTs[((ih * 2 + t) * 16 + lm) * CTS + ks * 32 + quad * 8];
                acc2[t] = __builtin_amdgcn_mfma_f32_16x16x32_bf16(a, bf, acc2[t], 0, 0, 0);
            }
        }
    }

    // ---- colsum reduce: over lm (16 i's) then over ih partials -> invqL ----
    #pragma unroll
    for (int r = 0; r < 4; ++r) {
        float v = csum[r];
        v += __shfl_xor(v, 1, 64); v += __shfl_xor(v, 2, 64);
        v += __shfl_xor(v, 4, 64); v += __shfl_xor(v, 8, 64);
        if (lm == 0) colAcc[ih * 32 + jh * 16 + quad * 4 + r] = v;
    }
    __syncthreads();
    if (tid < 32) {
        float cs = colAcc[tid] + colAcc[32 + tid] + colAcc[64 + tid] + colAcc[96 + tid];
        invqL[tid] = (qmL[tid] != 0.f) ? 1.0f / cs : 0.0f;
    }
    __syncthreads();

    // ---- TT16 epilogue: scale by invq, transpose via LDS, coalesced write ----
    short* Tb = CWs;   // safe: two syncs since last CWs read
    #pragma unroll
    for (int t = 0; t < 2; ++t) {
        int d = (ih * 2 + t) * 16 + lm;
        #pragma unroll
        for (int r = 0; r < 4; ++r) {
            int jl = jh * 16 + quad * 4 + r;
            Tb[d * TBS + jl] = f2bf(acc2[t][r] * invqL[jl]);
        }
    }
    __syncthreads();
    #pragma unroll
    for (int k = 0; k < 2; ++k) {
        int idx = tid + k * 512;
        int d = idx >> 3, j4 = idx & 7;
        *(short4_t*)&TT16[((size_t)(b * Dd + d)) * Lq + jq * 32 + j4 * 4] =
            *(short4_t*)&Tb[d * TBS + j4 * 4];
    }

    // ---- QT16 export (masked) from Qs: 128 d x 32 j ----
    {
        int d = tid >> 2, j8 = (tid & 3) * 8;
        short8_t o;
        #pragma unroll
        for (int r = 0; r < 8; ++r) {
            int j = j8 + r;
            o[r] = (qmL[j] != 0.f) ? Qs[j * AS + d] : (short)0;
        }
        *(short8_t*)&QT16[((size_t)(b * Dd + d)) * Lq + jq * 32 + j8] = o;
    }
}

// ============ k3: recompute P=exp(S), local s0/rowsum; A=(P@Qm)*rs, Bm=(P@T)*rs; out ============
__global__ __launch_bounds__(256, 3) void k3_out(
    const short* __restrict__ Q16, const short* __restrict__ QT16,
    const short* __restrict__ TT16, const float* __restrict__ C,
    const float* __restrict__ w_mul, const float* __restrict__ w_c,
    const int* __restrict__ Qmask,
    const float* __restrict__ s1f, const float* __restrict__ bias,
    float* __restrict__ out)
{
    __shared__ short Abuf[64 * AS];    // cw, then P (e bf16)
    __shared__ short Bbuf[128 * AS];   // Q -> QTs -> Af32 -> TTs -> Af32
    __shared__ float s0L[64], s1bL[128], qmLf[128];
    float* Af32 = (float*)Bbuf;

    int n = blockIdx.x;
    int b, blk; decode_bid(n, b, blk);
    int i0 = blk * 64, tid = threadIdx.x;
    int w = tid >> 6, lane = tid & 63, lm = lane & 15, quad = lane >> 4;

    // ---- stage Q16 -> Bbuf; C -> cw -> Abuf + local s0 ----
    const short8_t* Qg = (const short8_t*)(Q16 + (size_t)b * Lq * Dd);
    #pragma unroll
    for (int k = 0; k < 8; ++k) {
        int idx = tid + k * 256;
        int j = idx >> 4, h = idx & 15;
        *(short8_t*)&Bbuf[j * AS + h * 8] = Qg[idx];
    }
    const float4* C4 = (const float4*)(C + ((size_t)(b * Lc + i0)) * Dd);
    #pragma unroll
    for (int k = 0; k < 8; ++k) {
        int idx = tid + k * 256;
        int i = idx >> 5, d4 = idx & 31;
        float4 v = C4[idx];
        float4 wm = ((const float4*)w_mul)[d4];
        short4_t cw; cw[0]=f2bf(v.x*wm.x); cw[1]=f2bf(v.y*wm.y); cw[2]=f2bf(v.z*wm.z); cw[3]=f2bf(v.w*wm.w);
        *(short4_t*)&Abuf[i * AS + d4 * 4] = cw;
        float4 wc = ((const float4*)w_c)[d4];
        float dot = v.x*wc.x + v.y*wc.y + v.z*wc.z + v.w*wc.w;
        #pragma unroll
        for (int off = 1; off < 32; off <<= 1) dot += __shfl_xor(dot, off, 64);
        if ((tid & 31) == 0) s0L[i] = dot;
    }
    if (tid < 128) {
        s1bL[tid] = s1f[b * Lq + tid] + bias[0];
        qmLf[tid] = (Qmask[b * Lq + tid] != 0) ? 1.0f : 0.0f;
    }
    __syncthreads();

    // ---- S = Cw @ Q^T (bit-identical to kT's S^T) ----
    f32x4 acc[8];
    #pragma unroll
    for (int t = 0; t < 8; ++t) acc[t] = (f32x4){0.f,0.f,0.f,0.f};
    #pragma unroll
    for (int ks = 0; ks < 4; ++ks) {
        short8_t a = *(short8_t*)&Abuf[(w * 16 + lm) * AS + ks * 32 + quad * 8];
        #pragma unroll
        for (int jt = 0; jt < 8; ++jt) {
            short8_t bf = *(short8_t*)&Bbuf[(jt * 16 + lm) * AS + ks * 32 + quad * 8];
            acc[jt] = __builtin_amdgcn_mfma_f32_16x16x32_bf16(a, bf, acc[jt], 0, 0, 0);
        }
    }

    // ---- P = exp(S) bf16 -> Abuf (wave-own rows) + local rowsum ----
    float s0v[4];
    #pragma unroll
    for (int r = 0; r < 4; ++r) s0v[r] = s0L[w * 16 + quad * 4 + r];
    float rowpart[4] = {0.f, 0.f, 0.f, 0.f};
    #pragma unroll
    for (int jt = 0; jt < 8; ++jt) {
        int j = jt * 16 + lm;
        float s1b = s1bL[j];
        float qm = qmLf[j];
        #pragma unroll
        for (int r = 0; r < 4; ++r) {
            float e = __expf(acc[jt][r] + s0v[r] + s1b);
            Abuf[(w * 16 + quad * 4 + r) * AS + j] = f2bf(e);
            rowpart[r] += qm * e;
        }
    }
    float rs[4];
    #pragma unroll
    for (int r = 0; r < 4; ++r) {
        float v = rowpart[r];
        v += __shfl_xor(v, 1, 64); v += __shfl_xor(v, 2, 64);
        v += __shfl_xor(v, 4, 64); v += __shfl_xor(v, 8, 64);
        rs[r] = 1.0f / v;          // butterfly -> all lanes hold total
    }
    __syncthreads();

    // ---- stage QTs -> Bbuf; accQ = P @ QT ----
    const short8_t* QTg = (const short8_t*)(QT16 + (size_t)b * Dd * Lq);
    #pragma unroll
    for (int k = 0; k < 8; ++k) {
        int idx = tid + k * 256;
        int d = idx >> 4, h = idx & 15;
        *(short8_t*)&Bbuf[d * AS + h * 8] = QTg[idx];
    }
    __syncthreads();
    f32x4 accQ[8];
    #pragma unroll
    for (int t = 0; t < 8; ++t) accQ[t] = (f32x4){0.f,0.f,0.f,0.f};
    #pragma unroll
    for (int ks = 0; ks < 4; ++ks) {
        short8_t a = *(short8_t*)&Abuf[(w * 16 + lm) * AS + ks * 32 + quad * 8];
        #pragma unroll
        for (int dt = 0; dt < 8; ++dt) {
            short8_t bf = *(short8_t*)&Bbuf[(dt * 16 + lm) * AS + ks * 32 + quad * 8];
            accQ[dt] = __builtin_amdgcn_mfma_f32_16x16x32_bf16(a, bf, accQ[dt], 0, 0, 0);
        }
    }
    __syncthreads();

    // ---- epilogue A: Af32 = accQ*rs; stores of C, A, C*A ----
    #pragma unroll
    for (int dt = 0; dt < 8; ++dt)
        #pragma unroll
        for (int r = 0; r < 4; ++r)
            Af32[(w * 16 + quad * 4 + r) * AS + dt * 16 + lm] = accQ[dt][r] * rs[r];
    __syncthreads();

    #pragma unroll
    for (int k = 0; k < 8; ++k) {
        int idx = tid + k * 256;
        int i = idx >> 5, d4 = idx & 31;
        float4 av = *(float4*)&Af32[i * AS + d4 * 4];
        float4 c = C4[idx];
        size_t base = ((size_t)(b * Lc + i0 + i)) * (4 * Dd) + d4 * 4;
        *(float4*)&out[base]           = c;
        *(float4*)&out[base + Dd]      = av;
        float4 ca; ca.x = c.x*av.x; ca.y = c.y*av.y; ca.z = c.z*av.z; ca.w = c.w*av.w;
        *(float4*)&out[base + 2 * Dd]  = ca;
    }
    __syncthreads();

    // ---- stage TTs -> Bbuf; accT = P @ TT ----
    const short8_t* TTg = (const short8_t*)(TT16 + (size_t)b * Dd * Lq);
    #pragma unroll
    for (int k = 0; k < 8; ++k) {
        int idx = tid + k * 256;
        int d = idx >> 4, h = idx & 15;
        *(short8_t*)&Bbuf[d * AS + h * 8] = TTg[idx];
    }
    __syncthreads();
    f32x4 accT[8];
    #pragma unroll
    for (int t = 0; t < 8; ++t) accT[t] = (f32x4){0.f,0.f,0.f,0.f};
    #pragma unroll
    for (int ks = 0; ks < 4; ++ks) {
        short8_t a = *(short8_t*)&Abuf[(w * 16 + lm) * AS + ks * 32 + quad * 8];
        #pragma unroll
        for (int dt = 0; dt < 8; ++dt) {
            short8_t bf = *(short8_t*)&Bbuf[(dt * 16 + lm) * AS + ks * 32 + quad * 8];
            accT[dt] = __builtin_amdgcn_mfma_f32_16x16x32_bf16(a, bf, accT[dt], 0, 0, 0);
        }
    }
    __syncthreads();

    // ---- epilogue B: Af32 = accT*rs; store C*Bm ----
    #pragma unroll
    for (int dt = 0; dt < 8; ++dt)
        #pragma unroll
        for (int r = 0; r < 4; ++r)
            Af32[(w * 16 + quad * 4 + r) * AS + dt * 16 + lm] = accT[dt][r] * rs[r];
    __syncthreads();

    #pragma unroll
    for (int k = 0; k < 8; ++k) {
        int idx = tid + k * 256;
        int i = idx >> 5, d4 = idx & 31;
        float4 bm = *(float4*)&Af32[i * AS + d4 * 4];
        float4 c = C4[idx];
        size_t base = ((size_t)(b * Lc + i0 + i)) * (4 * Dd) + d4 * 4;
        float4 cb; cb.x = c.x*bm.x; cb.y = c.y*bm.y; cb.z = c.z*bm.z; cb.w = c.w*bm.w;
        *(float4*)&out[base + 3 * Dd]  = cb;
    }
}

extern "C" void kernel_launch(void* const* d_in, const int* in_sizes, int n_in,
                              void* d_out, int out_size, void* d_ws, size_t ws_size,
                              hipStream_t stream) {
    const float* C     = (const float*)d_in[0];
    const float* Q     = (const float*)d_in[1];
    const int*   Cmask = (const int*)d_in[2];
    const int*   Qmask = (const int*)d_in[3];
    const float* w_c   = (const float*)d_in[4];
    const float* w_q   = (const float*)d_in[5];
    const float* w_mul = (const float*)d_in[6];
    const float* bias  = (const float*)d_in[7];
    float* out = (float*)d_out;

    char* p = (char*)d_ws;
    const size_t NQ = (size_t)Bn * Lq * Dd;
    short* Q16  = (short*)p; p += NQ * 2;
    short* QT16 = (short*)p; p += NQ * 2;
    short* TT16 = (short*)p; p += NQ * 2;
    float* s1f  = (float*)p; p += (size_t)Bn * Lq * 4;

    kT<<<dim3(256), 512, 0, stream>>>(C, Q, Cmask, Qmask, w_c, w_q, w_mul, bias,
                                      Q16, QT16, s1f, TT16);
    k3_out<<<dim3(1024), 256, 0, stream>>>(Q16, QT16, TT16, C, w_mul, w_c, Qmask,
                                           s1f, bias, out);
}

// Round 4
// 214.564 us; speedup vs baseline: 1.2828x; 1.0265x over previous
//
#include <hip/hip_runtime.h>
#include <math.h>

constexpr int Bn = 64, Lc = 1024, Lq = 128, Dd = 128;

typedef __attribute__((ext_vector_type(8))) short short8_t;  // 8 bf16
typedef __attribute__((ext_vector_type(4))) short short4_t;  // 4 bf16
typedef __attribute__((ext_vector_type(4))) float f32x4;

__device__ __forceinline__ short f2bf(float x) {
    unsigned u = __float_as_uint(x);
    u += 0x7FFFu + ((u >> 16) & 1u);   // round-to-nearest-even
    return (short)(u >> 16);
}

constexpr int AS = 132;   // [row][d] LDS stride (shorts)
constexpr int CTS = 68;   // kT C^T staging stride (shorts)
constexpr int PS = 68;    // kT P^T tile stride (shorts)
constexpr int TBF = 36;   // kT f32 out-transpose stride (floats; mult of 4 for float4 align)

// ============ kT: Q prep/export + recompute E^T + T-partials; i-range split across 2 halves ============
// grid (512) = (2 half x 4 jq x 64 b), 512 threads, 2 blocks/CU. Each half does 8 chunks of 64 i.
__global__ __launch_bounds__(512) void kT(
    const float* __restrict__ C, const float* __restrict__ Q,
    const int* __restrict__ Cmask, const int* __restrict__ Qmask,
    const float* __restrict__ w_c, const float* __restrict__ w_q,
    const float* __restrict__ w_mul, const float* __restrict__ bias,
    short* __restrict__ Q16, short* __restrict__ QT16,
    float* __restrict__ s1f, float* __restrict__ Tpart, float* __restrict__ colpart)
{
    __shared__ short Qs[32 * AS];          // Q bf16 rows for this jq slice
    __shared__ short CWs[128 * TBF * 2];   // staging: [64][AS] shorts; epilogue: f32 [128][TBF] overlay
    __shared__ short CTs[128 * CTS];       // masked C^T chunk (128 d x 64 i)
    __shared__ short Ps[32 * PS];          // P^T tile (32 j x 64 i)
    __shared__ float s1bL[32], qmL[32], s0L[64], cmL[64];
    __shared__ float colAcc[128];

    int n = blockIdx.x;
    int b = (n & 7) * 8 + ((n >> 3) & 7);  // same-b blocks share XCD
    int rest = n >> 6, jq = rest & 3, half = rest >> 2;
    int tid = threadIdx.x, w = tid >> 6, lane = tid & 63;
    int lm = lane & 15, quad = lane >> 4;
    int jh = w & 1, ih = w >> 1;

    // ---- phase 0: Q f32 slice -> Qs bf16 (+ Q16 export by half0) + s1 + qm ----
    {
        int j = tid >> 4, d4 = tid & 15;
        const float4* Q4 = (const float4*)(Q + ((size_t)(b * Lq + jq * 32 + j)) * Dd);
        float4 v0 = Q4[d4], v1 = Q4[d4 + 16];
        short4_t q0, q1;
        q0[0]=f2bf(v0.x); q0[1]=f2bf(v0.y); q0[2]=f2bf(v0.z); q0[3]=f2bf(v0.w);
        q1[0]=f2bf(v1.x); q1[1]=f2bf(v1.y); q1[2]=f2bf(v1.z); q1[3]=f2bf(v1.w);
        *(short4_t*)&Qs[j * AS + d4 * 4] = q0;
        *(short4_t*)&Qs[j * AS + (d4 + 16) * 4] = q1;
        if (half == 0) {
            *(short4_t*)&Q16[((size_t)(b * Lq + jq * 32 + j)) * Dd + d4 * 4] = q0;
            *(short4_t*)&Q16[((size_t)(b * Lq + jq * 32 + j)) * Dd + (d4 + 16) * 4] = q1;
        }
        float4 wq0 = ((const float4*)w_q)[d4], wq1 = ((const float4*)w_q)[d4 + 16];
        float dot = v0.x*wq0.x + v0.y*wq0.y + v0.z*wq0.z + v0.w*wq0.w
                  + v1.x*wq1.x + v1.y*wq1.y + v1.z*wq1.z + v1.w*wq1.w;
        #pragma unroll
        for (int off = 1; off < 16; off <<= 1) dot += __shfl_xor(dot, off, 64);
        if (d4 == 0) {
            s1bL[j] = dot + bias[0];
            qmL[j] = (Qmask[b * Lq + jq * 32 + j] != 0) ? 1.0f : 0.0f;
            if (half == 0) s1f[b * Lq + jq * 32 + j] = dot;
        }
    }

    // ---- prefetch first chunk ----
    const float4* Cb4 = (const float4*)(C + (size_t)b * Lc * Dd);
    int iS = tid >> 5, dS = tid & 31;
    float4 wmv = ((const float4*)w_mul)[dS];
    float4 wcv = ((const float4*)w_c)[dS];
    int ic0 = half * 8;
    float4 pc[4]; int pm[4];
    #pragma unroll
    for (int k = 0; k < 4; ++k) {
        int gi = ic0 * 64 + iS + k * 16;
        pc[k] = Cb4[(size_t)gi * 32 + dS];
        pm[k] = Cmask[b * Lc + gi];
    }

    float csum[4] = {0.f, 0.f, 0.f, 0.f};
    f32x4 acc2[2];
    acc2[0] = (f32x4){0.f,0.f,0.f,0.f};
    acc2[1] = (f32x4){0.f,0.f,0.f,0.f};

    for (int ic = ic0; ic < ic0 + 8; ++ic) {
        __syncthreads();   // prev S/T reads done (also covers phase-0 Qs writes)
        #pragma unroll
        for (int k = 0; k < 4; ++k) {
            float4 v = pc[k];
            float cm = pm[k] ? 1.0f : 0.0f;
            int i = iS + k * 16;
            short4_t cw;
            cw[0]=f2bf(v.x*wmv.x); cw[1]=f2bf(v.y*wmv.y); cw[2]=f2bf(v.z*wmv.z); cw[3]=f2bf(v.w*wmv.w);
            *(short4_t*)&CWs[i * AS + dS * 4] = cw;
            CTs[(dS*4+0)*CTS + i] = f2bf(cm * v.x);
            CTs[(dS*4+1)*CTS + i] = f2bf(cm * v.y);
            CTs[(dS*4+2)*CTS + i] = f2bf(cm * v.z);
            CTs[(dS*4+3)*CTS + i] = f2bf(cm * v.w);
            float dot = v.x*wcv.x + v.y*wcv.y + v.z*wcv.z + v.w*wcv.w;
            #pragma unroll
            for (int off = 1; off < 32; off <<= 1) dot += __shfl_xor(dot, off, 64);
            if (dS == 0) { s0L[i] = dot; cmL[i] = cm; }
        }
        if (ic < ic0 + 7) {   // prefetch next chunk; latency hides under MFMA phases
            int ibn = (ic + 1) * 64;
            #pragma unroll
            for (int k = 0; k < 4; ++k) {
                pc[k] = Cb4[((size_t)(ibn + iS + k * 16)) * 32 + dS];
                pm[k] = Cmask[b * Lc + ibn + iS + k * 16];
            }
        }
        __syncthreads();

        // S^T tile [32j x 64i] across 8 waves; bit-identical to k3's S (operand swap)
        f32x4 sacc = (f32x4){0.f,0.f,0.f,0.f};
        #pragma unroll
        for (int ks = 0; ks < 4; ++ks) {
            short8_t a = *(short8_t*)&Qs[(jh * 16 + lm) * AS + ks * 32 + quad * 8];
            short8_t bq = *(short8_t*)&CWs[(ih * 16 + lm) * AS + ks * 32 + quad * 8];
            sacc = __builtin_amdgcn_mfma_f32_16x16x32_bf16(a, bq, sacc, 0, 0, 0);
        }
        float s0v = s0L[ih * 16 + lm];
        float cmv = cmL[ih * 16 + lm];
        #pragma unroll
        for (int r = 0; r < 4; ++r) {
            float e = __expf(sacc[r] + s0v + s1bL[jh * 16 + quad * 4 + r]);
            Ps[(jh * 16 + quad * 4 + r) * PS + ih * 16 + lm] = f2bf(e);
            csum[r] += cmv * e;
        }
        __syncthreads();

        // T partial: [16j x 32d] per wave, k = 64 i
        #pragma unroll
        for (int ks = 0; ks < 2; ++ks) {
            short8_t a = *(short8_t*)&Ps[(jh * 16 + lm) * PS + ks * 32 + quad * 8];
            #pragma unroll
            for (int t = 0; t < 2; ++t) {
                short8_t bf = *(short8_t*)&CTs[((ih * 2 + t) * 16 + lm) * CTS + ks * 32 + quad * 8];
                acc2[t] = __builtin_amdgcn_mfma_f32_16x16x32_bf16(a, bf, acc2[t], 0, 0, 0);
            }
        }
    }

    // ---- colsum partial reduce + T-partial f32 transpose via LDS ----
    #pragma unroll
    for (int r = 0; r < 4; ++r) {
        float v = csum[r];
        v += __shfl_xor(v, 1, 64); v += __shfl_xor(v, 2, 64);
        v += __shfl_xor(v, 4, 64); v += __shfl_xor(v, 8, 64);
        if (lm == 0) colAcc[ih * 32 + jh * 16 + quad * 4 + r] = v;
    }
    float* Tbf = (float*)CWs;   // safe: no CWs reads since mid-loop barrier of last chunk
    #pragma unroll
    for (int t = 0; t < 2; ++t) {
        int d = (ih * 2 + t) * 16 + lm;
        #pragma unroll
        for (int r = 0; r < 4; ++r)
            Tbf[d * TBF + jh * 16 + quad * 4 + r] = acc2[t][r];
    }
    __syncthreads();
    if (tid < 32)
        colpart[((size_t)(half * Bn + b)) * Lq + jq * 32 + tid] =
            colAcc[tid] + colAcc[32 + tid] + colAcc[64 + tid] + colAcc[96 + tid];
    #pragma unroll
    for (int k = 0; k < 2; ++k) {
        int idx = tid + k * 512;
        int d = idx >> 3, j4 = idx & 7;
        *(float4*)&Tpart[(((size_t)(half * Bn + b)) * Dd + d) * Lq + jq * 32 + j4 * 4] =
            *(float4*)&Tbf[d * TBF + j4 * 4];
    }

    // ---- QT16 export (masked) by half1: 128 d x 32 j ----
    if (half == 1) {
        int d = tid >> 2, j8 = (tid & 3) * 8;
        short8_t o;
        #pragma unroll
        for (int r = 0; r < 8; ++r) {
            int j = j8 + r;
            o[r] = (qmL[j] != 0.f) ? Qs[j * AS + d] : (short)0;
        }
        *(short8_t*)&QT16[((size_t)(b * Dd + d)) * Lq + jq * 32 + j8] = o;
    }
}

// ============ k3: recompute P=exp(S); A=(P@Qm)*rs, Bm=(P@(Tp0+Tp1)*invq)*rs; out ============
__global__ __launch_bounds__(256, 3) void k3_out(
    const short* __restrict__ Q16, const short* __restrict__ QT16,
    const float* __restrict__ Tpart, const float* __restrict__ colpart,
    const float* __restrict__ C, const float* __restrict__ w_mul,
    const float* __restrict__ w_c, const int* __restrict__ Qmask,
    const float* __restrict__ s1f, const float* __restrict__ bias,
    float* __restrict__ out)
{
    __shared__ short Abuf[64 * AS];    // cw, then P (e bf16)
    __shared__ short Bbuf[128 * AS];   // Q -> QTs -> Af32 -> TTs -> Af32
    __shared__ float s0L[64], s1bL[128], qmLf[128], invqL[128];
    float* Af32 = (float*)Bbuf;

    int n = blockIdx.x;
    int b = (n & 7) * 8 + ((n >> 3) & 7);
    int blk = n >> 6;
    int i0 = blk * 64, tid = threadIdx.x;
    int w = tid >> 6, lane = tid & 63, lm = lane & 15, quad = lane >> 4;

    // ---- stage Q16 -> Bbuf; C -> cv regs + cw -> Abuf + local s0 ----
    const short8_t* Qg = (const short8_t*)(Q16 + (size_t)b * Lq * Dd);
    #pragma unroll
    for (int k = 0; k < 8; ++k) {
        int idx = tid + k * 256;
        int j = idx >> 4, h = idx & 15;
        *(short8_t*)&Bbuf[j * AS + h * 8] = Qg[idx];
    }
    const float4* C4 = (const float4*)(C + ((size_t)(b * Lc + i0)) * Dd);
    float4 cv[8];
    #pragma unroll
    for (int k = 0; k < 8; ++k) {
        int idx = tid + k * 256;
        int i = idx >> 5, d4 = idx & 31;
        float4 v = C4[idx];
        cv[k] = v;
        float4 wm = ((const float4*)w_mul)[d4];
        short4_t cw; cw[0]=f2bf(v.x*wm.x); cw[1]=f2bf(v.y*wm.y); cw[2]=f2bf(v.z*wm.z); cw[3]=f2bf(v.w*wm.w);
        *(short4_t*)&Abuf[i * AS + d4 * 4] = cw;
        float4 wc = ((const float4*)w_c)[d4];
        float dot = v.x*wc.x + v.y*wc.y + v.z*wc.z + v.w*wc.w;
        #pragma unroll
        for (int off = 1; off < 32; off <<= 1) dot += __shfl_xor(dot, off, 64);
        if ((tid & 31) == 0) s0L[i] = dot;
    }
    if (tid < 128) {
        float qm = (Qmask[b * Lq + tid] != 0) ? 1.0f : 0.0f;
        qmLf[tid] = qm;
        s1bL[tid] = s1f[b * Lq + tid] + bias[0];
        float cs = colpart[(size_t)b * Lq + tid] + colpart[((size_t)(Bn + b)) * Lq + tid];
        invqL[tid] = (qm != 0.f) ? 1.0f / cs : 0.0f;
    }
    __syncthreads();

    // ---- S = Cw @ Q^T (bit-identical to kT's S^T) ----
    f32x4 acc[8];
    #pragma unroll
    for (int t = 0; t < 8; ++t) acc[t] = (f32x4){0.f,0.f,0.f,0.f};
    #pragma unroll
    for (int ks = 0; ks < 4; ++ks) {
        short8_t a = *(short8_t*)&Abuf[(w * 16 + lm) * AS + ks * 32 + quad * 8];
        #pragma unroll
        for (int jt = 0; jt < 8; ++jt) {
            short8_t bf = *(short8_t*)&Bbuf[(jt * 16 + lm) * AS + ks * 32 + quad * 8];
            acc[jt] = __builtin_amdgcn_mfma_f32_16x16x32_bf16(a, bf, acc[jt], 0, 0, 0);
        }
    }

    // ---- P = exp(S) bf16 -> Abuf (wave-own rows) + local rowsum ----
    float s0v[4];
    #pragma unroll
    for (int r = 0; r < 4; ++r) s0v[r] = s0L[w * 16 + quad * 4 + r];
    float rowpart[4] = {0.f, 0.f, 0.f, 0.f};
    #pragma unroll
    for (int jt = 0; jt < 8; ++jt) {
        int j = jt * 16 + lm;
        float s1b = s1bL[j];
        float qm = qmLf[j];
        #pragma unroll
        for (int r = 0; r < 4; ++r) {
            float e = __expf(acc[jt][r] + s0v[r] + s1b);
            Abuf[(w * 16 + quad * 4 + r) * AS + j] = f2bf(e);
            rowpart[r] += qm * e;
        }
    }
    float rs[4];
    #pragma unroll
    for (int r = 0; r < 4; ++r) {
        float v = rowpart[r];
        v += __shfl_xor(v, 1, 64); v += __shfl_xor(v, 2, 64);
        v += __shfl_xor(v, 4, 64); v += __shfl_xor(v, 8, 64);
        rs[r] = 1.0f / v;
    }
    __syncthreads();

    // ---- stage QTs -> Bbuf; accQ = P @ QT ----
    const short8_t* QTg = (const short8_t*)(QT16 + (size_t)b * Dd * Lq);
    #pragma unroll
    for (int k = 0; k < 8; ++k) {
        int idx = tid + k * 256;
        int d = idx >> 4, h = idx & 15;
        *(short8_t*)&Bbuf[d * AS + h * 8] = QTg[idx];
    }
    __syncthreads();
    f32x4 accQ[8];
    #pragma unroll
    for (int t = 0; t < 8; ++t) accQ[t] = (f32x4){0.f,0.f,0.f,0.f};
    #pragma unroll
    for (int ks = 0; ks < 4; ++ks) {
        short8_t a = *(short8_t*)&Abuf[(w * 16 + lm) * AS + ks * 32 + quad * 8];
        #pragma unroll
        for (int dt = 0; dt < 8; ++dt) {
            short8_t bf = *(short8_t*)&Bbuf[(dt * 16 + lm) * AS + ks * 32 + quad * 8];
            accQ[dt] = __builtin_amdgcn_mfma_f32_16x16x32_bf16(a, bf, accQ[dt], 0, 0, 0);
        }
    }
    __syncthreads();

    // ---- epilogue A: Af32 = accQ*rs; stores of C, A, C*A (C from regs) ----
    #pragma unroll
    for (int dt = 0; dt < 8; ++dt)
        #pragma unroll
        for (int r = 0; r < 4; ++r)
            Af32[(w * 16 + quad * 4 + r) * AS + dt * 16 + lm] = accQ[dt][r] * rs[r];
    __syncthreads();

    #pragma unroll
    for (int k = 0; k < 8; ++k) {
        int idx = tid + k * 256;
        int i = idx >> 5, d4 = idx & 31;
        float4 av = *(float4*)&Af32[i * AS + d4 * 4];
        float4 c = cv[k];
        size_t base = ((size_t)(b * Lc + i0 + i)) * (4 * Dd) + d4 * 4;
        *(float4*)&out[base]           = c;
        *(float4*)&out[base + Dd]      = av;
        float4 ca; ca.x = c.x*av.x; ca.y = c.y*av.y; ca.z = c.z*av.z; ca.w = c.w*av.w;
        *(float4*)&out[base + 2 * Dd]  = ca;
    }
    __syncthreads();

    // ---- stage TTs -> Bbuf from Tpart halves, scaled by invq; accT = P @ T ----
    const float4* T0 = (const float4*)(Tpart + (size_t)b * Dd * Lq);
    const float4* T1 = (const float4*)(Tpart + ((size_t)(Bn + b)) * Dd * Lq);
    #pragma unroll
    for (int k = 0; k < 16; ++k) {
        int idx = tid + k * 256;
        int d = idx >> 5, j4 = idx & 31;
        float4 x = T0[idx], y = T1[idx];
        short4_t o;
        o[0] = f2bf((x.x + y.x) * invqL[j4 * 4 + 0]);
        o[1] = f2bf((x.y + y.y) * invqL[j4 * 4 + 1]);
        o[2] = f2bf((x.z + y.z) * invqL[j4 * 4 + 2]);
        o[3] = f2bf((x.w + y.w) * invqL[j4 * 4 + 3]);
        *(short4_t*)&Bbuf[d * AS + j4 * 4] = o;
    }
    __syncthreads();
    f32x4 accT[8];
    #pragma unroll
    for (int t = 0; t < 8; ++t) accT[t] = (f32x4){0.f,0.f,0.f,0.f};
    #pragma unroll
    for (int ks = 0; ks < 4; ++ks) {
        short8_t a = *(short8_t*)&Abuf[(w * 16 + lm) * AS + ks * 32 + quad * 8];
        #pragma unroll
        for (int dt = 0; dt < 8; ++dt) {
            short8_t bf = *(short8_t*)&Bbuf[(dt * 16 + lm) * AS + ks * 32 + quad * 8];
            accT[dt] = __builtin_amdgcn_mfma_f32_16x16x32_bf16(a, bf, accT[dt], 0, 0, 0);
        }
    }
    __syncthreads();

    // ---- epilogue B: Af32 = accT*rs; store C*Bm (C from regs) ----
    #pragma unroll
    for (int dt = 0; dt < 8; ++dt)
        #pragma unroll
        for (int r = 0; r < 4; ++r)
            Af32[(w * 16 + quad * 4 + r) * AS + dt * 16 + lm] = accT[dt][r] * rs[r];
    __syncthreads();

    #pragma unroll
    for (int k = 0; k < 8; ++k) {
        int idx = tid + k * 256;
        int i = idx >> 5, d4 = idx & 31;
        float4 bm = *(float4*)&Af32[i * AS + d4 * 4];
        float4 c = cv[k];
        size_t base = ((size_t)(b * Lc + i0 + i)) * (4 * Dd) + d4 * 4;
        float4 cb; cb.x = c.x*bm.x; cb.y = c.y*bm.y; cb.z = c.z*bm.z; cb.w = c.w*bm.w;
        *(float4*)&out[base + 3 * Dd]  = cb;
    }
}

extern "C" void kernel_launch(void* const* d_in, const int* in_sizes, int n_in,
                              void* d_out, int out_size, void* d_ws, size_t ws_size,
                              hipStream_t stream) {
    const float* C     = (const float*)d_in[0];
    const float* Q     = (const float*)d_in[1];
    const int*   Cmask = (const int*)d_in[2];
    const int*   Qmask = (const int*)d_in[3];
    const float* w_c   = (const float*)d_in[4];
    const float* w_q   = (const float*)d_in[5];
    const float* w_mul = (const float*)d_in[6];
    const float* bias  = (const float*)d_in[7];
    float* out = (float*)d_out;

    char* p = (char*)d_ws;
    const size_t NQ = (size_t)Bn * Lq * Dd;
    short* Q16   = (short*)p; p += NQ * 2;
    short* QT16  = (short*)p; p += NQ * 2;
    float* Tpart = (float*)p; p += 2 * NQ * 4;
    float* colpart = (float*)p; p += 2 * (size_t)Bn * Lq * 4;
    float* s1f   = (float*)p; p += (size_t)Bn * Lq * 4;

    kT<<<dim3(512), 512, 0, stream>>>(C, Q, Cmask, Qmask, w_c, w_q, w_mul, bias,
                                      Q16, QT16, s1f, Tpart, colpart);
    k3_out<<<dim3(1024), 256, 0, stream>>>(Q16, QT16, Tpart, colpart, C, w_mul, w_c, Qmask,
                                           s1f, bias, out);
}